// Round 1
// 275.720 us; speedup vs baseline: 1.0571x; 1.0571x over previous
//
#include <hip/hip_runtime.h>
#include <hip/hip_bf16.h>

#define N_PTS 16384
#define TEMP_F 0.05f

typedef __attribute__((ext_vector_type(8))) short bf16x8;
typedef __attribute__((ext_vector_type(4))) float f32x4;

__device__ __forceinline__ float selu_f(float x) {
    const float scale = 1.0507009873554805f;
    const float alpha = 1.6732632423543772f;
    return x > 0.f ? scale * x : scale * alpha * (__expf(x) - 1.f);
}

__device__ __forceinline__ float fast_sqrtf(float x) {
#if __has_builtin(__builtin_amdgcn_sqrtf)
    return __builtin_amdgcn_sqrtf(x);   // v_sqrt_f32
#else
    return sqrtf(x);
#endif
}

__device__ __forceinline__ float fast_exp2f(float x) {
#if __has_builtin(__builtin_amdgcn_exp2f)
    return __builtin_amdgcn_exp2f(x);   // v_exp_f32
#else
    return exp2f(x);
#endif
}

__device__ __forceinline__ float fast_log2f(float x) {
#if __has_builtin(__builtin_amdgcn_logf)
    return __builtin_amdgcn_logf(x);    // v_log_f32
#else
    return log2f(x);
#endif
}

__device__ __forceinline__ f32x4 mfma_bf16(bf16x8 a, bf16x8 b, f32x4 c) {
    return __builtin_amdgcn_mfma_f32_16x16x32_bf16(a, b, c, 0, 0, 0);
}

// split fp32 v into truncated-bf16 hi + bf16(residual) lo; hi+lo ~ 16-bit mantissa
__device__ __forceinline__ void split_bf16(float v, unsigned short& hi, unsigned short& lo) {
    unsigned u = __float_as_uint(v);
    hi = (unsigned short)(u >> 16);
    float ah = __uint_as_float(u & 0xFFFF0000u);
    lo = (unsigned short)(__float_as_uint(v - ah) >> 16);
}

// ---------------------------------------------------------------------------
// pack_kernel: convert W1..W4 (fp32 row-major [K][256]) into hi/lo bf16 arrays
// laid out in exact per-lane MFMA B-fragment order:
//   ushort index = (((nt*KC + kc)*64) + lane)*8 + e
//   where n = nt*16 + (lane&15), k = kc*32 + (lane>>4)*8 + e
// Packed region layout (ushort offsets):
//   W1h:0  W1l:8192  then per mid layer ly: h at 16384+ly*131072, l = h+65536
// ---------------------------------------------------------------------------
__global__ __launch_bounds__(512) void pack_kernel(
    const float* __restrict__ W1, const float* __restrict__ W2,
    const float* __restrict__ W3, const float* __restrict__ W4,
    unsigned short* __restrict__ pk)
{
    int idx = blockIdx.x * 512 + threadIdx.x;
    if (idx >= 204800) return;
    const float* src;
    unsigned short *dh, *dl;
    int rem, kc, nt;
    if (idx < 8192) {                       // W1: K=32, KC=1
        src = W1; dh = pk; dl = pk + 8192;
        rem = idx;
        int g = rem >> 9;
        kc = 0; nt = g;
    } else {                                // W2..W4: K=256, KC=8
        int t2 = idx - 8192;
        int ly = t2 >> 16;
        rem = t2 & 65535;
        src = (ly == 0) ? W2 : (ly == 1) ? W3 : W4;
        dh = pk + 16384 + ly * 131072;
        dl = dh + 65536;
        int g = rem >> 9;
        kc = g & 7; nt = g >> 3;
    }
    int e = rem & 7;
    int l = (rem >> 3) & 63;
    int n = nt * 16 + (l & 15);
    int k = kc * 32 + ((l >> 4) << 3) + e;
    float v = src[k * 256 + n];
    unsigned short hb, lb;
    split_bf16(v, hb, lb);
    dh[rem] = hb;
    dl[rem] = lb;
}

// ---------------------------------------------------------------------------
// mlp_mfma_kernel: fused 5-layer MLP via split-bf16 MFMA (3 mfma per product:
// Ah*Bh + Ah*Bl + Al*Bh, fp32 accumulate -> ~2^-17 relative product error).
// Block: 512 threads = 8 waves, 64 rows. Wave wv: row-tile rt=wv>>1 (16 rows),
// col-half ch=wv&1 (128 cols = 8 n-tiles). Activations in LDS as hi/lo bf16
// [64][256] with XOR swizzle byte^=((row&7)<<4) (else ds_read_b128 A-frag is
// a 16-way bank conflict). Weights read straight from the packed global
// arrays: 16B/lane coalesced, L2-hot. 64KB LDS -> 2 blk/CU -> 4 waves/SIMD.
// ---------------------------------------------------------------------------
__global__ __launch_bounds__(512, 4) void mlp_mfma_kernel(
    const float* __restrict__ z,
    const unsigned short* __restrict__ pk,
    const float* __restrict__ b1, const float* __restrict__ b2,
    const float* __restrict__ b3, const float* __restrict__ b4,
    const float* __restrict__ W5, const float* __restrict__ b5,
    float* __restrict__ gen)
{
    __shared__ __align__(16) unsigned short Hh[64 * 256];   // 32 KB
    __shared__ __align__(16) unsigned short Hl[64 * 256];   // 32 KB

    const int t  = threadIdx.x;
    const int l  = t & 63;
    const int wv = t >> 6;          // 0..7
    const int rt = wv >> 1;         // row tile 0..3
    const int ch = wv & 1;          // col half 0..1
    const int lr = l & 15;          // fragment m (A) / n (B,D) index
    const int lq = l >> 4;          // 0..3, selects k-subblock / D row group
    const int row0 = blockIdx.x * 64;
    const int arow = rt * 16 + lr;  // block-local A row

    // ---------------- layer 1 (32 -> 256), K fits one MFMA ----------------
    {
        const float* zp = z + (row0 + arow) * 32 + lq * 8;
        f32x4 z0 = *(const f32x4*)(zp);
        f32x4 z1 = *(const f32x4*)(zp + 4);
        bf16x8 ahf, alf;
        #pragma unroll
        for (int e = 0; e < 8; e++) {
            float v = (e < 4) ? z0[e] : z1[e - 4];
            unsigned short hb, lb;
            split_bf16(v, hb, lb);
            ahf[e] = (short)hb; alf[e] = (short)lb;
        }
        const bf16x8* B1h = (const bf16x8*)(pk);
        const bf16x8* B1l = (const bf16x8*)(pk + 8192);
        f32x4 acc[8];
        #pragma unroll
        for (int tile = 0; tile < 8; tile++) {
            float bv = b1[ch * 128 + tile * 16 + lr];
            acc[tile] = (f32x4){bv, bv, bv, bv};
        }
        #pragma unroll
        for (int tile = 0; tile < 8; tile++) {
            int nt = ch * 8 + tile;
            bf16x8 bh = B1h[nt * 64 + l];
            bf16x8 bl = B1l[nt * 64 + l];
            acc[tile] = mfma_bf16(ahf, bh, acc[tile]);
            acc[tile] = mfma_bf16(ahf, bl, acc[tile]);
            acc[tile] = mfma_bf16(alf, bh, acc[tile]);
        }
        // D layout (verified m89): col = lane&15, row = (lane>>4)*4 + r
        #pragma unroll
        for (int tile = 0; tile < 8; tile++) {
            #pragma unroll
            for (int r = 0; r < 4; r++) {
                float v = selu_f(acc[tile][r]);
                int rowo = rt * 16 + lq * 4 + r;
                int n = ch * 128 + tile * 16 + lr;
                int o = (2 * n) ^ ((rowo & 7) << 4);
                unsigned short hb, lb;
                split_bf16(v, hb, lb);
                Hh[rowo * 256 + (o >> 1)] = hb;
                Hl[rowo * 256 + (o >> 1)] = lb;
            }
        }
    }
    __syncthreads();

    // ---------------- layers 2..4 (256 -> 256) ----------------
    #pragma unroll 1
    for (int ly = 0; ly < 3; ly++) {
        const unsigned short* wbase = pk + 16384 + ly * 131072;
        const bf16x8* Bh = (const bf16x8*)(wbase);
        const bf16x8* Bl = (const bf16x8*)(wbase + 65536);
        const float* bb = (ly == 0) ? b2 : (ly == 1) ? b3 : b4;
        f32x4 acc[8];
        #pragma unroll
        for (int tile = 0; tile < 8; tile++) {
            float bv = bb[ch * 128 + tile * 16 + lr];
            acc[tile] = (f32x4){bv, bv, bv, bv};
        }
        #pragma unroll 2
        for (int kc = 0; kc < 8; kc++) {
            int o = (kc * 64 + lq * 16) ^ ((arow & 7) << 4);
            bf16x8 ahf = *(const bf16x8*)(Hh + arow * 256 + (o >> 1));
            bf16x8 alf = *(const bf16x8*)(Hl + arow * 256 + (o >> 1));
            #pragma unroll
            for (int tile = 0; tile < 8; tile++) {
                int nt = ch * 8 + tile;
                bf16x8 bh = Bh[(nt * 8 + kc) * 64 + l];
                bf16x8 bl = Bl[(nt * 8 + kc) * 64 + l];
                acc[tile] = mfma_bf16(ahf, bh, acc[tile]);
                acc[tile] = mfma_bf16(ahf, bl, acc[tile]);
                acc[tile] = mfma_bf16(alf, bh, acc[tile]);
            }
        }
        __syncthreads();   // all waves done READING H before anyone overwrites
        #pragma unroll
        for (int tile = 0; tile < 8; tile++) {
            #pragma unroll
            for (int r = 0; r < 4; r++) {
                float v = selu_f(acc[tile][r]);
                int rowo = rt * 16 + lq * 4 + r;
                int n = ch * 128 + tile * 16 + lr;
                int o = (2 * n) ^ ((rowo & 7) << 4);
                unsigned short hb, lb;
                split_bf16(v, hb, lb);
                Hh[rowo * 256 + (o >> 1)] = hb;
                Hl[rowo * 256 + (o >> 1)] = lb;
            }
        }
        __syncthreads();   // writes visible before next layer's reads
    }

    // ---------------- layer 5 (256 -> 2), VALU, 128 threads ----------------
    if (t < 128) {
        int row = t & 63;
        int d = t >> 6;
        float sum = b5[d];
        #pragma unroll 4
        for (int k = 0; k < 256; k += 8) {
            int o = (2 * k) ^ ((row & 7) << 4);
            bf16x8 hh = *(const bf16x8*)(Hh + row * 256 + (o >> 1));
            bf16x8 ll = *(const bf16x8*)(Hl + row * 256 + (o >> 1));
            #pragma unroll
            for (int e = 0; e < 8; e++) {
                float hv = __uint_as_float(((unsigned)(unsigned short)hh[e]) << 16)
                         + __uint_as_float(((unsigned)(unsigned short)ll[e]) << 16);
                sum = fmaf(hv, W5[(k + e) * 2 + d], sum);
            }
        }
        gen[(row0 + row) * 2 + d] = sum;
    }
}

// ---------------------------------------------------------------------------
// Fallback fp32 MLP (previous round's kernel) — used only if ws too small.
// ---------------------------------------------------------------------------
__global__ __launch_bounds__(1024) void mlp_kernel(
    const float* __restrict__ z,
    const float* __restrict__ W1, const float* __restrict__ b1,
    const float* __restrict__ W2, const float* __restrict__ b2,
    const float* __restrict__ W3, const float* __restrict__ b3,
    const float* __restrict__ W4, const float* __restrict__ b4,
    const float* __restrict__ W5, const float* __restrict__ b5,
    float* __restrict__ gen)
{
    __shared__ float h[256 * 64];   // h[k*64 + r]

    const int t = threadIdx.x;
    const int r = t & 63;
    const int w = __builtin_amdgcn_readfirstlane(t >> 6);   // 0..15, uniform
    const int c0 = w * 16;
    const int row0 = blockIdx.x * 64;

    #pragma unroll
    for (int e = 0; e < 2; e++) {
        int f  = t + e * 1024;
        int rz = f >> 5;
        int kz = f & 31;
        h[kz * 64 + rz] = z[(row0 + rz) * 32 + kz];
    }
    __syncthreads();

    float acc[16];

    #pragma unroll
    for (int j = 0; j < 16; j++) acc[j] = b1[c0 + j];
    #pragma unroll 8
    for (int k = 0; k < 32; k++) {
        float hv = h[k * 64 + r];
        const float* Wr = W1 + k * 256 + c0;
        #pragma unroll
        for (int j = 0; j < 16; j++) acc[j] = fmaf(hv, Wr[j], acc[j]);
    }
    __syncthreads();
    #pragma unroll
    for (int j = 0; j < 16; j++) h[(c0 + j) * 64 + r] = selu_f(acc[j]);
    __syncthreads();

    for (int layer = 0; layer < 3; layer++) {
        const float* W = (layer == 0) ? W2 : (layer == 1) ? W3 : W4;
        const float* b = (layer == 0) ? b2 : (layer == 1) ? b3 : b4;
        #pragma unroll
        for (int j = 0; j < 16; j++) acc[j] = b[c0 + j];
        #pragma unroll 4
        for (int k = 0; k < 256; k++) {
            float hv = h[k * 64 + r];
            const float* Wr = W + k * 256 + c0;
            #pragma unroll
            for (int j = 0; j < 16; j++) acc[j] = fmaf(hv, Wr[j], acc[j]);
        }
        __syncthreads();
        #pragma unroll
        for (int j = 0; j < 16; j++) h[(c0 + j) * 64 + r] = selu_f(acc[j]);
        __syncthreads();
    }

    float p0 = 0.f, p1 = 0.f;
    #pragma unroll
    for (int kk = 0; kk < 16; kk++) {
        int k = c0 + kk;
        float hv = h[k * 64 + r];
        p0 = fmaf(hv, W5[k * 2 + 0], p0);
        p1 = fmaf(hv, W5[k * 2 + 1], p1);
    }
    __syncthreads();
    h[(0 * 16 + w) * 64 + r] = p0;
    h[(1 * 16 + w) * 64 + r] = p1;
    __syncthreads();
    if (t < 128) {
        int d  = t >> 6;
        int rr = t & 63;
        float sum = b5[d];
        #pragma unroll
        for (int ss = 0; ss < 16; ss++) sum += h[(d * 16 + ss) * 64 + rr];
        gen[(row0 + rr) * 2 + d] = sum;
    }
}

// ---------------------------------------------------------------------------
// Kernel B: SINGLE-PASS softmin-distance energy, fp32 in/out. (unchanged)
// ---------------------------------------------------------------------------
__global__ __launch_bounds__(512) void energy_kernel(
    const float* __restrict__ gen,
    const float* __restrict__ pos,
    float* __restrict__ out)
{
    __shared__ float4 sp[512];   // 1024 pos points
    __shared__ float4 sg[512];   // 1024 gen points

    const int t  = threadIdx.x;
    const int s  = t & 31;       // lane within row-group
    const int rl = t >> 5;       // 0..15 row within block
    const int i  = blockIdx.x * 16 + rl;
    const int diagBase = ((blockIdx.x * 16) >> 10) << 10;   // block-uniform

    const float2 q = ((const float2*)gen)[i];

    const float cL2 = 28.853900817779268f;   // 1/(T*ln2) = 20*log2(e)
    const float Tl2 = 0.034657359027997264f; // T*ln2
    const float cB  = 57.707801635558536f;   // cL2 * B, B = 2.0

    float p0 = 0.f, p1 = 0.f, n0 = 0.f, n1 = 0.f;

    for (int base = 0; base < N_PTS; base += 1024) {
        __syncthreads();
        sp[t] = ((const float4*)pos)[base / 2 + t];
        sg[t] = ((const float4*)gen)[base / 2 + t];
        __syncthreads();
        if (base == diagBase) {
            #pragma unroll 4
            for (int u = 0; u < 16; u++) {
                int j = base + 2 * (s + 32 * u);
                float4 pp = sp[s + 32 * u];
                float4 gg = sg[s + 32 * u];
                float dx = q.x - pp.x, dy = q.y - pp.y;
                float d  = fast_sqrtf(fmaf(dx, dx, dy * dy));
                p0 += fast_exp2f(fmaf(-cL2, d, cB));
                dx = q.x - pp.z; dy = q.y - pp.w;
                d  = fast_sqrtf(fmaf(dx, dx, dy * dy));
                p1 += fast_exp2f(fmaf(-cL2, d, cB));
                dx = q.x - gg.x; dy = q.y - gg.y;
                d  = fast_sqrtf(fmaf(dx, dx, dy * dy));
                float e0 = fast_exp2f(fmaf(-cL2, d, cB));
                n0 += (j == i) ? 0.f : e0;
                dx = q.x - gg.z; dy = q.y - gg.w;
                d  = fast_sqrtf(fmaf(dx, dx, dy * dy));
                float e1 = fast_exp2f(fmaf(-cL2, d, cB));
                n1 += (j + 1 == i) ? 0.f : e1;
            }
        } else {
            #pragma unroll 4
            for (int u = 0; u < 16; u++) {
                float4 pp = sp[s + 32 * u];
                float4 gg = sg[s + 32 * u];
                float dx = q.x - pp.x, dy = q.y - pp.y;
                float d  = fast_sqrtf(fmaf(dx, dx, dy * dy));
                p0 += fast_exp2f(fmaf(-cL2, d, cB));
                dx = q.x - pp.z; dy = q.y - pp.w;
                d  = fast_sqrtf(fmaf(dx, dx, dy * dy));
                p1 += fast_exp2f(fmaf(-cL2, d, cB));
                dx = q.x - gg.x; dy = q.y - gg.y;
                d  = fast_sqrtf(fmaf(dx, dx, dy * dy));
                n0 += fast_exp2f(fmaf(-cL2, d, cB));
                dx = q.x - gg.z; dy = q.y - gg.w;
                d  = fast_sqrtf(fmaf(dx, dx, dy * dy));
                n1 += fast_exp2f(fmaf(-cL2, d, cB));
            }
        }
    }

    float sump = p0 + p1;
    float sumn = n0 + n1;
    #pragma unroll
    for (int m = 1; m < 32; m <<= 1) {
        sump += __shfl_xor(sump, m, 32);
        sumn += __shfl_xor(sumn, m, 32);
    }

    if (s == 0) {
        out[i] = Tl2 * (fast_log2f(sumn) - fast_log2f(sump));
    }
}

// ---------------------------------------------------------------------------
extern "C" void kernel_launch(void* const* d_in, const int* in_sizes, int n_in,
                              void* d_out, int out_size, void* d_ws, size_t ws_size,
                              hipStream_t stream) {
    const float* pos = (const float*)d_in[0];
    const float* z   = (const float*)d_in[1];
    const float* W1  = (const float*)d_in[2];
    const float* b1  = (const float*)d_in[3];
    const float* W2  = (const float*)d_in[4];
    const float* b2  = (const float*)d_in[5];
    const float* W3  = (const float*)d_in[6];
    const float* b3  = (const float*)d_in[7];
    const float* W4  = (const float*)d_in[8];
    const float* b4  = (const float*)d_in[9];
    const float* W5  = (const float*)d_in[10];
    const float* b5  = (const float*)d_in[11];

    float* gen = (float*)d_ws;                               // 16384 x 2 fp32
    unsigned short* pk = (unsigned short*)((char*)d_ws + 131072);
    const size_t WS_NEEDED = 131072 + (size_t)409600 * 2;    // gen + packed W

    if (ws_size >= WS_NEEDED) {
        pack_kernel<<<400, 512, 0, stream>>>(W1, W2, W3, W4, pk);
        mlp_mfma_kernel<<<N_PTS / 64, 512, 0, stream>>>(z, pk, b1, b2, b3, b4,
                                                        W5, b5, gen);
    } else {
        mlp_kernel<<<N_PTS / 64, 1024, 0, stream>>>(z, W1, b1, W2, b2, W3, b3,
                                                    W4, b4, W5, b5, gen);
    }
    energy_kernel<<<N_PTS / 16, 512, 0, stream>>>(gen, pos, (float*)d_out);
}

// Round 2
// 235.163 us; speedup vs baseline: 1.2394x; 1.1725x over previous
//
#include <hip/hip_runtime.h>
#include <hip/hip_bf16.h>

#define N_PTS 16384
#define TEMP_F 0.05f

typedef __attribute__((ext_vector_type(8))) short bf16x8;
typedef __attribute__((ext_vector_type(4))) float f32x4;

__device__ __forceinline__ float selu_f(float x) {
    const float scale = 1.0507009873554805f;
    const float alpha = 1.6732632423543772f;
    return x > 0.f ? scale * x : scale * alpha * (__expf(x) - 1.f);
}

__device__ __forceinline__ float fast_sqrtf(float x) {
#if __has_builtin(__builtin_amdgcn_sqrtf)
    return __builtin_amdgcn_sqrtf(x);   // v_sqrt_f32
#else
    return sqrtf(x);
#endif
}

__device__ __forceinline__ float fast_exp2f(float x) {
#if __has_builtin(__builtin_amdgcn_exp2f)
    return __builtin_amdgcn_exp2f(x);   // v_exp_f32
#else
    return exp2f(x);
#endif
}

__device__ __forceinline__ float fast_log2f(float x) {
#if __has_builtin(__builtin_amdgcn_logf)
    return __builtin_amdgcn_logf(x);    // v_log_f32
#else
    return log2f(x);
#endif
}

__device__ __forceinline__ f32x4 mfma_bf16(bf16x8 a, bf16x8 b, f32x4 c) {
    return __builtin_amdgcn_mfma_f32_16x16x32_bf16(a, b, c, 0, 0, 0);
}

// split fp32 v into truncated-bf16 hi + bf16(residual) lo; hi+lo ~ 16-bit mantissa
__device__ __forceinline__ void split_bf16(float v, unsigned short& hi, unsigned short& lo) {
    unsigned u = __float_as_uint(v);
    hi = (unsigned short)(u >> 16);
    float ah = __uint_as_float(u & 0xFFFF0000u);
    lo = (unsigned short)(__float_as_uint(v - ah) >> 16);
}

// ---------------------------------------------------------------------------
// pack_kernel v2: COALESCED reads (thread per (k,n), consecutive lanes ->
// consecutive n), scattered 2B stores (fire-and-forget, no stall).
// Packed per-lane MFMA B-fragment order (unchanged from verified round 1):
//   ushort index rem = ((nt*KC + kc)*64 + lq*16 + lr)*8 + e
//   with n = nt*16 + lr, k = kc*32 + lq*8 + e
// Region layout (ushort offsets): W1h:0 W1l:8192; layer ly in {0,1,2}:
//   h at 16384 + ly*131072, l = h + 65536
// ---------------------------------------------------------------------------
__global__ __launch_bounds__(256) void pack_kernel(
    const float* __restrict__ W1, const float* __restrict__ W2,
    const float* __restrict__ W3, const float* __restrict__ W4,
    unsigned short* __restrict__ pk)
{
    int idx = blockIdx.x * 256 + threadIdx.x;
    if (idx >= 204800) return;
    const float* src;
    unsigned short *dh, *dl;
    int k, n, KC;
    if (idx < 8192) {                       // W1: K=32
        src = W1; dh = pk; dl = pk + 8192; KC = 1;
        k = idx >> 8; n = idx & 255;
    } else {                                // W2..W4: K=256
        int t2 = idx - 8192;
        int ly = t2 >> 16;
        int r2 = t2 & 65535;
        src = (ly == 0) ? W2 : (ly == 1) ? W3 : W4;
        dh = pk + 16384 + ly * 131072;
        dl = dh + 65536;
        KC = 8;
        k = r2 >> 8; n = r2 & 255;
    }
    int nt = n >> 4, lr = n & 15;
    int kc = k >> 5, lq = (k >> 3) & 3, e = k & 7;
    int rem = ((nt * KC + kc) * 64 + lq * 16 + lr) * 8 + e;
    float v = src[k * 256 + n];
    unsigned short hb, lb;
    split_bf16(v, hb, lb);
    dh[rem] = hb;
    dl[rem] = lb;
}

// ---------------------------------------------------------------------------
// mlp_mfma_kernel v2: fused 5-layer MLP via split-bf16 MFMA
// (Ah*Bh + Ah*Bl + Al*Bh, fp32 accumulate).
// Re-tiled: 8 waves, each wave owns a DISTINCT 32-col slice (n-tiles
// 2wv,2wv+1) x ALL 64 rows (m-tiles 0..3) -> zero weight-fetch redundancy
// within a block (was 4x). 24 MFMA per kc per wave.
// NO min-waves launch_bounds clause: round 1's (512,4) forced a 128-VGPR cap
// and spilled the inner loop to scratch. Live set here ~100 VGPR.
// LDS 64KB (Hh/Hl bf16 [64][256], XOR swizzle byte^=((row&7)<<4) -> b128
// A-reads run at the bank-BW floor). 2 blk/CU by LDS; grid=256 -> 1 blk/CU.
// ---------------------------------------------------------------------------
__global__ __launch_bounds__(512) void mlp_mfma_kernel(
    const float* __restrict__ z,
    const unsigned short* __restrict__ pk,
    const float* __restrict__ b1, const float* __restrict__ b2,
    const float* __restrict__ b3, const float* __restrict__ b4,
    const float* __restrict__ W5, const float* __restrict__ b5,
    float* __restrict__ gen)
{
    __shared__ __align__(16) unsigned short Hh[64 * 256];   // 32 KB
    __shared__ __align__(16) unsigned short Hl[64 * 256];   // 32 KB

    const int t  = threadIdx.x;
    const int l  = t & 63;
    const int wv = t >> 6;          // 0..7: owns n-tiles {2wv, 2wv+1}
    const int lr = l & 15;          // fragment m (A) / n (B,D) index
    const int lq = l >> 4;          // 0..3: k-subblock / D row group
    const int row0 = blockIdx.x * 64;

    f32x4 acc[4][2];

    // ---------------- layer 1 (32 -> 256), K fits one MFMA ----------------
    {
        bf16x8 ah[4], al[4];
        #pragma unroll
        for (int m = 0; m < 4; m++) {
            const float* zp = z + (row0 + m * 16 + lr) * 32 + lq * 8;
            f32x4 z0 = *(const f32x4*)(zp);
            f32x4 z1 = *(const f32x4*)(zp + 4);
            #pragma unroll
            for (int e = 0; e < 8; e++) {
                float v = (e < 4) ? z0[e] : z1[e - 4];
                unsigned short hb, lb;
                split_bf16(v, hb, lb);
                ah[m][e] = (short)hb; al[m][e] = (short)lb;
            }
        }
        #pragma unroll
        for (int n2 = 0; n2 < 2; n2++) {
            float bv = b1[wv * 32 + n2 * 16 + lr];
            #pragma unroll
            for (int m = 0; m < 4; m++) acc[m][n2] = (f32x4){bv, bv, bv, bv};
        }
        const bf16x8* B1h = (const bf16x8*)(pk);
        const bf16x8* B1l = (const bf16x8*)(pk + 8192);
        #pragma unroll
        for (int n2 = 0; n2 < 2; n2++) {
            int nt = wv * 2 + n2;
            bf16x8 bh = B1h[nt * 64 + l];
            bf16x8 bl = B1l[nt * 64 + l];
            #pragma unroll
            for (int m = 0; m < 4; m++) {
                acc[m][n2] = mfma_bf16(ah[m], bh, acc[m][n2]);
                acc[m][n2] = mfma_bf16(ah[m], bl, acc[m][n2]);
                acc[m][n2] = mfma_bf16(al[m], bh, acc[m][n2]);
            }
        }
        // D layout (verified m89): col = lane&15, row = (lane>>4)*4 + r
        #pragma unroll
        for (int m = 0; m < 4; m++) {
            #pragma unroll
            for (int n2 = 0; n2 < 2; n2++) {
                #pragma unroll
                for (int r = 0; r < 4; r++) {
                    float v = selu_f(acc[m][n2][r]);
                    int rowo = m * 16 + lq * 4 + r;
                    int n = wv * 32 + n2 * 16 + lr;
                    int o = (2 * n) ^ ((rowo & 7) << 4);
                    unsigned short hb, lb;
                    split_bf16(v, hb, lb);
                    Hh[rowo * 256 + (o >> 1)] = hb;
                    Hl[rowo * 256 + (o >> 1)] = lb;
                }
            }
        }
    }
    __syncthreads();

    // ---------------- layers 2..4 (256 -> 256) ----------------
    #pragma unroll 1
    for (int ly = 0; ly < 3; ly++) {
        const unsigned short* wbase = pk + 16384 + ly * 131072;
        const bf16x8* Bh = (const bf16x8*)(wbase);
        const bf16x8* Bl = (const bf16x8*)(wbase + 65536);
        const float* bb = (ly == 0) ? b2 : (ly == 1) ? b3 : b4;
        #pragma unroll
        for (int n2 = 0; n2 < 2; n2++) {
            float bv = bb[wv * 32 + n2 * 16 + lr];
            #pragma unroll
            for (int m = 0; m < 4; m++) acc[m][n2] = (f32x4){bv, bv, bv, bv};
        }
        #pragma unroll 1
        for (int kc = 0; kc < 8; kc++) {
            bf16x8 ah[4], al[4];
            #pragma unroll
            for (int m = 0; m < 4; m++) {
                int arow = m * 16 + lr;
                int o = (kc * 64 + lq * 16) ^ ((arow & 7) << 4);
                ah[m] = *(const bf16x8*)(Hh + arow * 256 + (o >> 1));
                al[m] = *(const bf16x8*)(Hl + arow * 256 + (o >> 1));
            }
            #pragma unroll
            for (int n2 = 0; n2 < 2; n2++) {
                bf16x8 bh = Bh[((wv * 2 + n2) * 8 + kc) * 64 + l];
                bf16x8 bl = Bl[((wv * 2 + n2) * 8 + kc) * 64 + l];
                #pragma unroll
                for (int m = 0; m < 4; m++) {
                    acc[m][n2] = mfma_bf16(ah[m], bh, acc[m][n2]);
                    acc[m][n2] = mfma_bf16(ah[m], bl, acc[m][n2]);
                    acc[m][n2] = mfma_bf16(al[m], bh, acc[m][n2]);
                }
            }
        }
        __syncthreads();   // all waves done READING H before anyone overwrites
        #pragma unroll
        for (int m = 0; m < 4; m++) {
            #pragma unroll
            for (int n2 = 0; n2 < 2; n2++) {
                #pragma unroll
                for (int r = 0; r < 4; r++) {
                    float v = selu_f(acc[m][n2][r]);
                    int rowo = m * 16 + lq * 4 + r;
                    int n = wv * 32 + n2 * 16 + lr;
                    int o = (2 * n) ^ ((rowo & 7) << 4);
                    unsigned short hb, lb;
                    split_bf16(v, hb, lb);
                    Hh[rowo * 256 + (o >> 1)] = hb;
                    Hl[rowo * 256 + (o >> 1)] = lb;
                }
            }
        }
        __syncthreads();   // writes visible before next layer's reads
    }

    // ---------------- layer 5 (256 -> 2), VALU, 128 threads ----------------
    if (t < 128) {
        int row = t & 63;
        int d = t >> 6;
        float sum = b5[d];
        #pragma unroll 4
        for (int k = 0; k < 256; k += 8) {
            int o = (2 * k) ^ ((row & 7) << 4);
            bf16x8 hh = *(const bf16x8*)(Hh + row * 256 + (o >> 1));
            bf16x8 ll = *(const bf16x8*)(Hl + row * 256 + (o >> 1));
            #pragma unroll
            for (int e = 0; e < 8; e++) {
                float hv = __uint_as_float(((unsigned)(unsigned short)hh[e]) << 16)
                         + __uint_as_float(((unsigned)(unsigned short)ll[e]) << 16);
                sum = fmaf(hv, W5[(k + e) * 2 + d], sum);
            }
        }
        gen[(row0 + row) * 2 + d] = sum;
    }
}

// ---------------------------------------------------------------------------
// Fallback fp32 MLP — used only if workspace too small for packed weights.
// ---------------------------------------------------------------------------
__global__ __launch_bounds__(1024) void mlp_kernel(
    const float* __restrict__ z,
    const float* __restrict__ W1, const float* __restrict__ b1,
    const float* __restrict__ W2, const float* __restrict__ b2,
    const float* __restrict__ W3, const float* __restrict__ b3,
    const float* __restrict__ W4, const float* __restrict__ b4,
    const float* __restrict__ W5, const float* __restrict__ b5,
    float* __restrict__ gen)
{
    __shared__ float h[256 * 64];   // h[k*64 + r]

    const int t = threadIdx.x;
    const int r = t & 63;
    const int w = __builtin_amdgcn_readfirstlane(t >> 6);   // 0..15, uniform
    const int c0 = w * 16;
    const int row0 = blockIdx.x * 64;

    #pragma unroll
    for (int e = 0; e < 2; e++) {
        int f  = t + e * 1024;
        int rz = f >> 5;
        int kz = f & 31;
        h[kz * 64 + rz] = z[(row0 + rz) * 32 + kz];
    }
    __syncthreads();

    float acc[16];

    #pragma unroll
    for (int j = 0; j < 16; j++) acc[j] = b1[c0 + j];
    #pragma unroll 8
    for (int k = 0; k < 32; k++) {
        float hv = h[k * 64 + r];
        const float* Wr = W1 + k * 256 + c0;
        #pragma unroll
        for (int j = 0; j < 16; j++) acc[j] = fmaf(hv, Wr[j], acc[j]);
    }
    __syncthreads();
    #pragma unroll
    for (int j = 0; j < 16; j++) h[(c0 + j) * 64 + r] = selu_f(acc[j]);
    __syncthreads();

    for (int layer = 0; layer < 3; layer++) {
        const float* W = (layer == 0) ? W2 : (layer == 1) ? W3 : W4;
        const float* b = (layer == 0) ? b2 : (layer == 1) ? b3 : b4;
        #pragma unroll
        for (int j = 0; j < 16; j++) acc[j] = b[c0 + j];
        #pragma unroll 4
        for (int k = 0; k < 256; k++) {
            float hv = h[k * 64 + r];
            const float* Wr = W + k * 256 + c0;
            #pragma unroll
            for (int j = 0; j < 16; j++) acc[j] = fmaf(hv, Wr[j], acc[j]);
        }
        __syncthreads();
        #pragma unroll
        for (int j = 0; j < 16; j++) h[(c0 + j) * 64 + r] = selu_f(acc[j]);
        __syncthreads();
    }

    float p0 = 0.f, p1 = 0.f;
    #pragma unroll
    for (int kk = 0; kk < 16; kk++) {
        int k = c0 + kk;
        float hv = h[k * 64 + r];
        p0 = fmaf(hv, W5[k * 2 + 0], p0);
        p1 = fmaf(hv, W5[k * 2 + 1], p1);
    }
    __syncthreads();
    h[(0 * 16 + w) * 64 + r] = p0;
    h[(1 * 16 + w) * 64 + r] = p1;
    __syncthreads();
    if (t < 128) {
        int d  = t >> 6;
        int rr = t & 63;
        float sum = b5[d];
        #pragma unroll
        for (int ss = 0; ss < 16; ss++) sum += h[(d * 16 + ss) * 64 + rr];
        gen[(row0 + rr) * 2 + d] = sum;
    }
}

// ---------------------------------------------------------------------------
// Kernel B: SINGLE-PASS softmin-distance energy, fp32 in/out. (unchanged)
// ---------------------------------------------------------------------------
__global__ __launch_bounds__(512) void energy_kernel(
    const float* __restrict__ gen,
    const float* __restrict__ pos,
    float* __restrict__ out)
{
    __shared__ float4 sp[512];   // 1024 pos points
    __shared__ float4 sg[512];   // 1024 gen points

    const int t  = threadIdx.x;
    const int s  = t & 31;       // lane within row-group
    const int rl = t >> 5;       // 0..15 row within block
    const int i  = blockIdx.x * 16 + rl;
    const int diagBase = ((blockIdx.x * 16) >> 10) << 10;   // block-uniform

    const float2 q = ((const float2*)gen)[i];

    const float cL2 = 28.853900817779268f;   // 1/(T*ln2) = 20*log2(e)
    const float Tl2 = 0.034657359027997264f; // T*ln2
    const float cB  = 57.707801635558536f;   // cL2 * B, B = 2.0

    float p0 = 0.f, p1 = 0.f, n0 = 0.f, n1 = 0.f;

    for (int base = 0; base < N_PTS; base += 1024) {
        __syncthreads();
        sp[t] = ((const float4*)pos)[base / 2 + t];
        sg[t] = ((const float4*)gen)[base / 2 + t];
        __syncthreads();
        if (base == diagBase) {
            #pragma unroll 4
            for (int u = 0; u < 16; u++) {
                int j = base + 2 * (s + 32 * u);
                float4 pp = sp[s + 32 * u];
                float4 gg = sg[s + 32 * u];
                float dx = q.x - pp.x, dy = q.y - pp.y;
                float d  = fast_sqrtf(fmaf(dx, dx, dy * dy));
                p0 += fast_exp2f(fmaf(-cL2, d, cB));
                dx = q.x - pp.z; dy = q.y - pp.w;
                d  = fast_sqrtf(fmaf(dx, dx, dy * dy));
                p1 += fast_exp2f(fmaf(-cL2, d, cB));
                dx = q.x - gg.x; dy = q.y - gg.y;
                d  = fast_sqrtf(fmaf(dx, dx, dy * dy));
                float e0 = fast_exp2f(fmaf(-cL2, d, cB));
                n0 += (j == i) ? 0.f : e0;
                dx = q.x - gg.z; dy = q.y - gg.w;
                d  = fast_sqrtf(fmaf(dx, dx, dy * dy));
                float e1 = fast_exp2f(fmaf(-cL2, d, cB));
                n1 += (j + 1 == i) ? 0.f : e1;
            }
        } else {
            #pragma unroll 4
            for (int u = 0; u < 16; u++) {
                float4 pp = sp[s + 32 * u];
                float4 gg = sg[s + 32 * u];
                float dx = q.x - pp.x, dy = q.y - pp.y;
                float d  = fast_sqrtf(fmaf(dx, dx, dy * dy));
                p0 += fast_exp2f(fmaf(-cL2, d, cB));
                dx = q.x - pp.z; dy = q.y - pp.w;
                d  = fast_sqrtf(fmaf(dx, dx, dy * dy));
                p1 += fast_exp2f(fmaf(-cL2, d, cB));
                dx = q.x - gg.x; dy = q.y - gg.y;
                d  = fast_sqrtf(fmaf(dx, dx, dy * dy));
                n0 += fast_exp2f(fmaf(-cL2, d, cB));
                dx = q.x - gg.z; dy = q.y - gg.w;
                d  = fast_sqrtf(fmaf(dx, dx, dy * dy));
                n1 += fast_exp2f(fmaf(-cL2, d, cB));
            }
        }
    }

    float sump = p0 + p1;
    float sumn = n0 + n1;
    #pragma unroll
    for (int m = 1; m < 32; m <<= 1) {
        sump += __shfl_xor(sump, m, 32);
        sumn += __shfl_xor(sumn, m, 32);
    }

    if (s == 0) {
        out[i] = Tl2 * (fast_log2f(sumn) - fast_log2f(sump));
    }
}

// ---------------------------------------------------------------------------
extern "C" void kernel_launch(void* const* d_in, const int* in_sizes, int n_in,
                              void* d_out, int out_size, void* d_ws, size_t ws_size,
                              hipStream_t stream) {
    const float* pos = (const float*)d_in[0];
    const float* z   = (const float*)d_in[1];
    const float* W1  = (const float*)d_in[2];
    const float* b1  = (const float*)d_in[3];
    const float* W2  = (const float*)d_in[4];
    const float* b2  = (const float*)d_in[5];
    const float* W3  = (const float*)d_in[6];
    const float* b3  = (const float*)d_in[7];
    const float* W4  = (const float*)d_in[8];
    const float* b4  = (const float*)d_in[9];
    const float* W5  = (const float*)d_in[10];
    const float* b5  = (const float*)d_in[11];

    float* gen = (float*)d_ws;                               // 16384 x 2 fp32
    unsigned short* pk = (unsigned short*)((char*)d_ws + 131072);
    const size_t WS_NEEDED = 131072 + (size_t)409600 * 2;    // gen + packed W

    if (ws_size >= WS_NEEDED) {
        pack_kernel<<<800, 256, 0, stream>>>(W1, W2, W3, W4, pk);
        mlp_mfma_kernel<<<N_PTS / 64, 512, 0, stream>>>(z, pk, b1, b2, b3, b4,
                                                        W5, b5, gen);
    } else {
        mlp_kernel<<<N_PTS / 64, 1024, 0, stream>>>(z, W1, b1, W2, b2, W3, b3,
                                                    W4, b4, W5, b5, gen);
    }
    energy_kernel<<<N_PTS / 16, 512, 0, stream>>>(gen, pos, (float*)d_out);
}